// Round 1
// baseline (678.203 us; speedup 1.0000x reference)
//
#include <hip/hip_runtime.h>

// Problem dims
#define DP   257    // d+1 rows
#define NP   2049   // n+1 cols
#define NSEQ 2048   // n
#define NB   16     // batch

// ---------------------------------------------------------------------------
// G[b] = H[b,:,0:2048] @ H[b,:,0:2048]^T   (257x257, K=2048)
// 64x64 tile per block, 256 threads, 4x4 micro-tile per thread.
// LDS tiles stored k-major (As[k][row]) so per-thread fragments are float4.
// ---------------------------------------------------------------------------
__global__ __launch_bounds__(256) void gram_kernel(const float* __restrict__ H,
                                                   float* __restrict__ G) {
    const int b  = blockIdx.z;
    const int d0 = blockIdx.y * 64;
    const int e0 = blockIdx.x * 64;
    const float* __restrict__ Hb = H + (size_t)b * DP * NP;

    __shared__ float As[32][68];  // As[k][d]  (68 = 64 + pad, 16B-aligned rows)
    __shared__ float Bs[32][68];  // Bs[k][e]

    const int tid = threadIdx.x;
    const int tx  = tid & 15;
    const int ty  = tid >> 4;
    const int lc  = tid & 31;   // k within chunk
    const int lr  = tid >> 5;   // 0..7

    float acc[4][4] = {};

    for (int k0 = 0; k0 < NSEQ; k0 += 32) {
#pragma unroll
        for (int r = 0; r < 8; ++r) {
            const int row = lr + r * 8;          // 0..63
            const int gd  = d0 + row;
            const int ge  = e0 + row;
            As[lc][row] = (gd < DP) ? Hb[(size_t)gd * NP + (k0 + lc)] : 0.f;
            Bs[lc][row] = (ge < DP) ? Hb[(size_t)ge * NP + (k0 + lc)] : 0.f;
        }
        __syncthreads();
#pragma unroll
        for (int kk = 0; kk < 32; ++kk) {
            const float4 av = *reinterpret_cast<const float4*>(&As[kk][ty * 4]);
            const float4 bv = *reinterpret_cast<const float4*>(&Bs[kk][tx * 4]);
            const float a[4] = {av.x, av.y, av.z, av.w};
            const float c[4] = {bv.x, bv.y, bv.z, bv.w};
#pragma unroll
            for (int i = 0; i < 4; ++i)
#pragma unroll
                for (int j = 0; j < 4; ++j) acc[i][j] += a[i] * c[j];
        }
        __syncthreads();
    }

    float* __restrict__ Gb = G + (size_t)b * DP * DP;
#pragma unroll
    for (int i = 0; i < 4; ++i) {
        const int gd = d0 + ty * 4 + i;
        if (gd >= DP) continue;
#pragma unroll
        for (int j = 0; j < 4; ++j) {
            const int ge = e0 + tx * 4 + j;
            if (ge < DP) Gb[gd * DP + ge] = acc[i][j];
        }
    }
}

// ---------------------------------------------------------------------------
// Generic 257x257 matmul: C[b] = A[b?] @ B[b?]  (row-major, lda=ldb=ldc=257)
// strideA/strideB = 0 means the operand is shared across batches.
// ---------------------------------------------------------------------------
__global__ __launch_bounds__(256) void mm257_kernel(const float* __restrict__ A,
                                                    const float* __restrict__ B,
                                                    float* __restrict__ C,
                                                    int strideA, int strideB) {
    const int b  = blockIdx.z;
    const int m0 = blockIdx.y * 64;
    const int n0 = blockIdx.x * 64;
    const float* __restrict__ Ab = A + (size_t)b * strideA;
    const float* __restrict__ Bb = B + (size_t)b * strideB;
    float* __restrict__ Cb = C + (size_t)b * DP * DP;

    __shared__ float As[32][68];  // As[k][m] (A tile transposed)
    __shared__ float Bs[32][68];  // Bs[k][n]

    const int tid = threadIdx.x;
    const int tx  = tid & 15;
    const int ty  = tid >> 4;

    float acc[4][4] = {};

    for (int k0 = 0; k0 < DP; k0 += 32) {
        {   // A tile: 64 m-rows x 32 k-cols, transpose into As[k][m]
            const int lc = tid & 31;  // k
            const int lr = tid >> 5;  // 0..7
#pragma unroll
            for (int r = 0; r < 8; ++r) {
                const int m  = lr + r * 8;
                const int gm = m0 + m, gk = k0 + lc;
                As[lc][m] = (gm < DP && gk < DP) ? Ab[gm * DP + gk] : 0.f;
            }
        }
        {   // B tile: 32 k-rows x 64 n-cols into Bs[k][n]
            const int lc = tid & 63;  // n
            const int lr = tid >> 6;  // 0..3
#pragma unroll
            for (int r = 0; r < 8; ++r) {
                const int kk = lr + r * 4;
                const int gk = k0 + kk, gn = n0 + lc;
                Bs[kk][lc] = (gk < DP && gn < DP) ? Bb[gk * DP + gn] : 0.f;
            }
        }
        __syncthreads();
#pragma unroll
        for (int kk = 0; kk < 32; ++kk) {
            const float4 av = *reinterpret_cast<const float4*>(&As[kk][ty * 4]);
            const float4 bv = *reinterpret_cast<const float4*>(&Bs[kk][tx * 4]);
            const float a[4] = {av.x, av.y, av.z, av.w};
            const float c[4] = {bv.x, bv.y, bv.z, bv.w};
#pragma unroll
            for (int i = 0; i < 4; ++i)
#pragma unroll
                for (int j = 0; j < 4; ++j) acc[i][j] += a[i] * c[j];
        }
        __syncthreads();
    }

#pragma unroll
    for (int i = 0; i < 4; ++i) {
        const int gm = m0 + ty * 4 + i;
        if (gm >= DP) continue;
#pragma unroll
        for (int j = 0; j < 4; ++j) {
            const int gn = n0 + tx * 4 + j;
            if (gn < DP) Cb[gm * DP + gn] = acc[i][j];
        }
    }
}

// ---------------------------------------------------------------------------
// out[b,d,t] = H[b,d,t] + (1/n) * sum_e K[b,d,e] * H[b,e,t]
// M=257 (d), N=2049 (t), Kdim=257 (e)
// ---------------------------------------------------------------------------
__global__ __launch_bounds__(256) void attn_kernel(const float* __restrict__ H,
                                                   const float* __restrict__ K,
                                                   float* __restrict__ Out) {
    const int b  = blockIdx.z;
    const int d0 = blockIdx.y * 64;
    const int t0 = blockIdx.x * 64;
    const float* __restrict__ Hb = H + (size_t)b * DP * NP;
    const float* __restrict__ Kb = K + (size_t)b * DP * DP;
    float* __restrict__ Ob = Out + (size_t)b * DP * NP;

    __shared__ float As[32][68];  // As[e][d]  (K tile transposed)
    __shared__ float Bs[32][68];  // Bs[e][t]  (H tile, natural)

    const int tid = threadIdx.x;
    const int tx  = tid & 15;
    const int ty  = tid >> 4;

    float acc[4][4] = {};

    for (int k0 = 0; k0 < DP; k0 += 32) {
        {   // K tile: 64 d-rows x 32 e-cols -> As[e][d]
            const int lc = tid & 31;  // e
            const int lr = tid >> 5;  // 0..7
#pragma unroll
            for (int r = 0; r < 8; ++r) {
                const int dd = lr + r * 8;
                const int gd = d0 + dd, ge = k0 + lc;
                As[lc][dd] = (gd < DP && ge < DP) ? Kb[gd * DP + ge] : 0.f;
            }
        }
        {   // H tile: 32 e-rows x 64 t-cols -> Bs[e][t]
            const int lc = tid & 63;  // t
            const int lr = tid >> 6;  // 0..3
#pragma unroll
            for (int r = 0; r < 8; ++r) {
                const int ee = lr + r * 4;
                const int ge = k0 + ee, gt = t0 + lc;
                Bs[ee][lc] = (ge < DP && gt < NP) ? Hb[(size_t)ge * NP + gt] : 0.f;
            }
        }
        __syncthreads();
#pragma unroll
        for (int kk = 0; kk < 32; ++kk) {
            const float4 av = *reinterpret_cast<const float4*>(&As[kk][ty * 4]);
            const float4 bv = *reinterpret_cast<const float4*>(&Bs[kk][tx * 4]);
            const float a[4] = {av.x, av.y, av.z, av.w};
            const float c[4] = {bv.x, bv.y, bv.z, bv.w};
#pragma unroll
            for (int i = 0; i < 4; ++i)
#pragma unroll
                for (int j = 0; j < 4; ++j) acc[i][j] += a[i] * c[j];
        }
        __syncthreads();
    }

    const float inv_n = 1.0f / (float)NSEQ;
#pragma unroll
    for (int i = 0; i < 4; ++i) {
        const int gd = d0 + ty * 4 + i;
        if (gd >= DP) continue;
#pragma unroll
        for (int j = 0; j < 4; ++j) {
            const int gt = t0 + tx * 4 + j;
            if (gt < NP) {
                const size_t idx = (size_t)gd * NP + gt;
                Ob[idx] = Hb[idx] + inv_n * acc[i][j];
            }
        }
    }
}

extern "C" void kernel_launch(void* const* d_in, const int* in_sizes, int n_in,
                              void* d_out, int out_size, void* d_ws, size_t ws_size,
                              hipStream_t stream) {
    const float* H = (const float*)d_in[0];
    const float* P = (const float*)d_in[1];
    const float* Q = (const float*)d_in[2];
    float* out = (float*)d_out;

    // workspace layout: G, T, K   (each NB*DP*DP fp32 = ~4.23 MB)
    float* G = (float*)d_ws;
    float* T = G + (size_t)NB * DP * DP;
    float* K = T + (size_t)NB * DP * DP;

    const dim3 blk(256);

    // 1) G[b] = H_hat @ H_hat^T
    gram_kernel<<<dim3(5, 5, NB), blk, 0, stream>>>(H, G);
    // 2) T[b] = G[b] @ Q  (A batched, B shared)
    mm257_kernel<<<dim3(5, 5, NB), blk, 0, stream>>>(G, Q, T, DP * DP, 0);
    // 3) K[b] = P @ T[b]  (A shared, B batched)
    mm257_kernel<<<dim3(5, 5, NB), blk, 0, stream>>>(P, T, K, 0, DP * DP);
    // 4) out = H + (K @ H) / n
    attn_kernel<<<dim3(33, 5, NB), blk, 0, stream>>>(H, K, out);
}

// Round 2
// 214.126 us; speedup vs baseline: 3.1673x; 3.1673x over previous
//
#include <hip/hip_runtime.h>
#include <hip/hip_bf16.h>

#define DP   257
#define NP   2049
#define NSEQ 2048
#define NB   16
#define KLD  288          // padded k-dim / leading dim for small matrices (9*32)
#define TROWS 2080        // padded t rows for Hbt (65*32)

typedef __attribute__((ext_vector_type(8))) short bf16x8;
typedef __attribute__((ext_vector_type(4))) float f32x4;

// ---------------------------------------------------------------------------
// Convert H -> Hb (row-major bf16, 288 rows x 2048 cols, = masked H-hat)
//           -> Hbt (transposed bf16, 2080 rows x 288 cols, zero-padded)
// ---------------------------------------------------------------------------
__global__ __launch_bounds__(256) void conv_h(const float* __restrict__ H,
                                              __hip_bfloat16* __restrict__ Hb,
                                              __hip_bfloat16* __restrict__ Hbt) {
    const int b  = blockIdx.z;
    const int t0 = blockIdx.x * 64;
    const int e0 = blockIdx.y * 64;
    const float* __restrict__ Hs = H + (size_t)b * DP * NP;
    __hip_bfloat16* __restrict__ Hbb  = Hb  + (size_t)b * 288 * 2048;
    __hip_bfloat16* __restrict__ Hbtb = Hbt + (size_t)b * TROWS * KLD;

    __shared__ float tile[64][65];

    const int tl = threadIdx.x & 63;
    const int er = threadIdx.x >> 6;
#pragma unroll
    for (int r = 0; r < 16; ++r) {
        const int el = er + r * 4;        // 0..63
        const int ge = e0 + el;
        const int gt = t0 + tl;
        float v = 0.f;
        if (ge < DP && gt < NP) v = Hs[(size_t)ge * NP + gt];
        tile[el][tl] = v;
        if (ge < 288 && gt < 2048) Hbb[(size_t)ge * 2048 + gt] = __float2bfloat16(v);
    }
    __syncthreads();
#pragma unroll
    for (int r = 0; r < 16; ++r) {
        const int ttl = er + r * 4;       // t-local
        const int gt = t0 + ttl;
        const int ge = e0 + tl;           // e-local = lane -> contiguous writes
        if (gt < TROWS && ge < KLD)
            Hbtb[(size_t)gt * KLD + ge] = __float2bfloat16(tile[tl][ttl]);
    }
}

// ---------------------------------------------------------------------------
// Pb[m][k] = P[m][k] (bf16, zero-padded to 288x288); Qt[n][k] = Q[k][n]
// ---------------------------------------------------------------------------
__global__ __launch_bounds__(256) void conv_pq(const float* __restrict__ P,
                                               const float* __restrict__ Q,
                                               __hip_bfloat16* __restrict__ Pb,
                                               __hip_bfloat16* __restrict__ Qt) {
    const int c0 = blockIdx.x * 64;
    const int r0 = blockIdx.y * 64;
    const int tl = threadIdx.x & 63;
    const int rr = threadIdx.x >> 6;
    __shared__ float tile[64][65];

    if (blockIdx.z == 0) {
        // P straight copy-convert
#pragma unroll
        for (int r = 0; r < 16; ++r) {
            const int m = r0 + rr + r * 4;
            const int k = c0 + tl;
            float v = (m < DP && k < DP) ? P[m * DP + k] : 0.f;
            if (m < KLD && k < KLD) Pb[m * KLD + k] = __float2bfloat16(v);
        }
    } else {
        // Q transpose
#pragma unroll
        for (int r = 0; r < 16; ++r) {
            const int k = r0 + rr + r * 4;
            const int n = c0 + tl;
            float v = (k < DP && n < DP) ? Q[k * DP + n] : 0.f;
            tile[k - r0][n - c0] = v;
        }
        __syncthreads();
#pragma unroll
        for (int r = 0; r < 16; ++r) {
            const int k = r0 + tl;
            const int n = c0 + rr + r * 4;
            if (n < KLD && k < KLD) Qt[n * KLD + k] = __float2bfloat16(tile[tl][n - c0]);
        }
    }
}

// ---------------------------------------------------------------------------
// G[b] = Hb[b] @ Hb[b]^T   (K=2048). One wave per 32x32 tile, 4 MFMA/step.
// Output bf16, 288x288, zero outside 257x257.
// ---------------------------------------------------------------------------
__global__ __launch_bounds__(256) void gram_mfma(const __hip_bfloat16* __restrict__ Hb,
                                                 __hip_bfloat16* __restrict__ G) {
    const int gw   = blockIdx.x * 4 + (threadIdx.x >> 6);
    const int b    = gw / 81;
    const int tile = gw % 81;
    const int tm = tile / 9, tn = tile % 9;
    const int lane = threadIdx.x & 63;
    const int lrow = lane & 15;
    const int koff = (lane >> 4) * 8;
    const short* __restrict__ base = (const short*)(Hb + (size_t)b * 288 * 2048);
    const int m0 = tm * 32, n0 = tn * 32;

    f32x4 acc[2][2] = {};
    for (int k0 = 0; k0 < NSEQ; k0 += 32) {
        bf16x8 a0 = *(const bf16x8*)(base + (size_t)(m0 + lrow)      * 2048 + k0 + koff);
        bf16x8 a1 = *(const bf16x8*)(base + (size_t)(m0 + 16 + lrow) * 2048 + k0 + koff);
        bf16x8 c0 = *(const bf16x8*)(base + (size_t)(n0 + lrow)      * 2048 + k0 + koff);
        bf16x8 c1 = *(const bf16x8*)(base + (size_t)(n0 + 16 + lrow) * 2048 + k0 + koff);
        acc[0][0] = __builtin_amdgcn_mfma_f32_16x16x32_bf16(a0, c0, acc[0][0], 0, 0, 0);
        acc[0][1] = __builtin_amdgcn_mfma_f32_16x16x32_bf16(a0, c1, acc[0][1], 0, 0, 0);
        acc[1][0] = __builtin_amdgcn_mfma_f32_16x16x32_bf16(a1, c0, acc[1][0], 0, 0, 0);
        acc[1][1] = __builtin_amdgcn_mfma_f32_16x16x32_bf16(a1, c1, acc[1][1], 0, 0, 0);
    }
    __hip_bfloat16* __restrict__ Gb = G + (size_t)b * KLD * KLD;
    const int ccol  = lane & 15;
    const int crow0 = (lane >> 4) * 4;
#pragma unroll
    for (int i = 0; i < 2; ++i)
#pragma unroll
        for (int j = 0; j < 2; ++j)
#pragma unroll
            for (int r = 0; r < 4; ++r) {
                const int gm = m0 + i * 16 + crow0 + r;
                const int gn = n0 + j * 16 + ccol;
                const float v = (gm < DP && gn < DP) ? acc[i][j][r] : 0.f;
                Gb[gm * KLD + gn] = __float2bfloat16(v);
            }
}

// ---------------------------------------------------------------------------
// C[b][m][n] = sum_k A[m][k] * B[n][k]  (both row-major along k, ld=288, K=288)
// Output bf16, zero-masked outside 257x257.
// ---------------------------------------------------------------------------
__global__ __launch_bounds__(256) void mm_mfma(const __hip_bfloat16* __restrict__ A,
                                               const __hip_bfloat16* __restrict__ B,
                                               __hip_bfloat16* __restrict__ C,
                                               int strideA, int strideB) {
    const int gw   = blockIdx.x * 4 + (threadIdx.x >> 6);
    const int b    = gw / 81;
    const int tile = gw % 81;
    const int tm = tile / 9, tn = tile % 9;
    const int lane = threadIdx.x & 63;
    const int lrow = lane & 15;
    const int koff = (lane >> 4) * 8;
    const short* __restrict__ Ab = (const short*)(A + (size_t)b * strideA);
    const short* __restrict__ Bb = (const short*)(B + (size_t)b * strideB);
    const int m0 = tm * 32, n0 = tn * 32;

    f32x4 acc[2][2] = {};
#pragma unroll
    for (int k0 = 0; k0 < KLD; k0 += 32) {
        bf16x8 a0 = *(const bf16x8*)(Ab + (m0 + lrow)      * KLD + k0 + koff);
        bf16x8 a1 = *(const bf16x8*)(Ab + (m0 + 16 + lrow) * KLD + k0 + koff);
        bf16x8 c0 = *(const bf16x8*)(Bb + (n0 + lrow)      * KLD + k0 + koff);
        bf16x8 c1 = *(const bf16x8*)(Bb + (n0 + 16 + lrow) * KLD + k0 + koff);
        acc[0][0] = __builtin_amdgcn_mfma_f32_16x16x32_bf16(a0, c0, acc[0][0], 0, 0, 0);
        acc[0][1] = __builtin_amdgcn_mfma_f32_16x16x32_bf16(a0, c1, acc[0][1], 0, 0, 0);
        acc[1][0] = __builtin_amdgcn_mfma_f32_16x16x32_bf16(a1, c0, acc[1][0], 0, 0, 0);
        acc[1][1] = __builtin_amdgcn_mfma_f32_16x16x32_bf16(a1, c1, acc[1][1], 0, 0, 0);
    }
    __hip_bfloat16* __restrict__ Cb = C + (size_t)b * KLD * KLD;
    const int ccol  = lane & 15;
    const int crow0 = (lane >> 4) * 4;
#pragma unroll
    for (int i = 0; i < 2; ++i)
#pragma unroll
        for (int j = 0; j < 2; ++j)
#pragma unroll
            for (int r = 0; r < 4; ++r) {
                const int gm = m0 + i * 16 + crow0 + r;
                const int gn = n0 + j * 16 + ccol;
                const float v = (gm < DP && gn < DP) ? acc[i][j][r] : 0.f;
                Cb[gm * KLD + gn] = __float2bfloat16(v);
            }
}

// ---------------------------------------------------------------------------
// out[b][d][t] = H[b][d][t] + (1/n) * sum_e Kb[d][e] * Hbt[t][e]
// A = Kb rows (m=d), B = Hbt rows (n=t)  ->  C[d][t] natural orientation,
// stores are t-contiguous per quad.
// ---------------------------------------------------------------------------
__global__ __launch_bounds__(256) void attn_mfma(const __hip_bfloat16* __restrict__ Kb,
                                                 const __hip_bfloat16* __restrict__ Hbt,
                                                 const float* __restrict__ H,
                                                 float* __restrict__ Out) {
    const int gw   = blockIdx.x * 4 + (threadIdx.x >> 6);
    const int b    = gw / 585;            // 585 = 9 (d-tiles) * 65 (t-tiles)
    const int tile = gw % 585;
    const int td = tile / 65, tt = tile % 65;
    const int lane = threadIdx.x & 63;
    const int lrow = lane & 15;
    const int koff = (lane >> 4) * 8;
    const short* __restrict__ Ab = (const short*)(Kb  + (size_t)b * KLD * KLD);
    const short* __restrict__ Bb = (const short*)(Hbt + (size_t)b * TROWS * KLD);
    const int m0 = td * 32, n0 = tt * 32;

    f32x4 acc[2][2] = {};
#pragma unroll
    for (int k0 = 0; k0 < KLD; k0 += 32) {
        bf16x8 a0 = *(const bf16x8*)(Ab + (m0 + lrow)      * KLD + k0 + koff);
        bf16x8 a1 = *(const bf16x8*)(Ab + (m0 + 16 + lrow) * KLD + k0 + koff);
        bf16x8 c0 = *(const bf16x8*)(Bb + (size_t)(n0 + lrow)      * KLD + k0 + koff);
        bf16x8 c1 = *(const bf16x8*)(Bb + (size_t)(n0 + 16 + lrow) * KLD + k0 + koff);
        acc[0][0] = __builtin_amdgcn_mfma_f32_16x16x32_bf16(a0, c0, acc[0][0], 0, 0, 0);
        acc[0][1] = __builtin_amdgcn_mfma_f32_16x16x32_bf16(a0, c1, acc[0][1], 0, 0, 0);
        acc[1][0] = __builtin_amdgcn_mfma_f32_16x16x32_bf16(a1, c0, acc[1][0], 0, 0, 0);
        acc[1][1] = __builtin_amdgcn_mfma_f32_16x16x32_bf16(a1, c1, acc[1][1], 0, 0, 0);
    }
    const float* __restrict__ Hs = H + (size_t)b * DP * NP;
    float* __restrict__ Ob = Out + (size_t)b * DP * NP;
    const float inv_n = 1.0f / (float)NSEQ;
    const int ccol  = lane & 15;
    const int crow0 = (lane >> 4) * 4;
#pragma unroll
    for (int i = 0; i < 2; ++i)
#pragma unroll
        for (int j = 0; j < 2; ++j)
#pragma unroll
            for (int r = 0; r < 4; ++r) {
                const int gd = m0 + i * 16 + crow0 + r;
                const int gt = n0 + j * 16 + ccol;
                if (gd < DP && gt < NP) {
                    const size_t idx = (size_t)gd * NP + gt;
                    Ob[idx] = Hs[idx] + inv_n * acc[i][j][r];
                }
            }
}

extern "C" void kernel_launch(void* const* d_in, const int* in_sizes, int n_in,
                              void* d_out, int out_size, void* d_ws, size_t ws_size,
                              hipStream_t stream) {
    const float* H = (const float*)d_in[0];
    const float* P = (const float*)d_in[1];
    const float* Q = (const float*)d_in[2];
    float* out = (float*)d_out;

    __hip_bfloat16* Hb  = (__hip_bfloat16*)d_ws;                   // 16*288*2048
    __hip_bfloat16* Hbt = Hb  + (size_t)NB * 288 * 2048;           // 16*2080*288
    __hip_bfloat16* G   = Hbt + (size_t)NB * TROWS * KLD;          // 16*288*288
    __hip_bfloat16* T2  = G   + (size_t)NB * KLD * KLD;
    __hip_bfloat16* Kb  = T2  + (size_t)NB * KLD * KLD;
    __hip_bfloat16* Pb  = Kb  + (size_t)NB * KLD * KLD;
    __hip_bfloat16* Qt  = Pb  + (size_t)KLD * KLD;

    conv_h <<<dim3(33, 5, NB), 256, 0, stream>>>(H, Hb, Hbt);
    conv_pq<<<dim3(5, 5, 2),   256, 0, stream>>>(P, Q, Pb, Qt);
    // G[b] = H-hat @ H-hat^T  (symmetric)
    gram_mfma<<<dim3(324), 256, 0, stream>>>(Hb, G);
    // T2[b] = Q^T @ G[b]   (B-frags read G rows, valid by symmetry)
    mm_mfma<<<dim3(324), 256, 0, stream>>>(Qt, G, T2, 0, KLD * KLD);
    // K[b] = P @ T2[b]^T = P @ G @ Q
    mm_mfma<<<dim3(324), 256, 0, stream>>>(Pb, T2, Kb, 0, KLD * KLD);
    // out = H + (K @ H) / n
    attn_mfma<<<dim3(2340), 256, 0, stream>>>(Kb, Hbt, H, out);
}

// Round 3
// 209.696 us; speedup vs baseline: 3.2342x; 1.0211x over previous
//
#include <hip/hip_runtime.h>
#include <hip/hip_bf16.h>

#define DP   257
#define NP   2049
#define NSEQ 2048
#define NB   16
#define KLD  288          // padded k-dim / leading dim for small matrices (9*32)
#define TROWS 2112        // padded t rows for Hbt (33*64)

typedef __attribute__((ext_vector_type(8))) short bf16x8;
typedef __attribute__((ext_vector_type(4))) short bf16x4;
typedef __attribute__((ext_vector_type(4))) float f32x4;

// ---------------------------------------------------------------------------
// Convert H -> Hb (row-major bf16, 288 rows x 2048 cols, = masked H-hat)
//           -> Hbt (transposed bf16, 2112 rows x 288 cols, zero-padded)
// ---------------------------------------------------------------------------
__global__ __launch_bounds__(256) void conv_h(const float* __restrict__ H,
                                              __hip_bfloat16* __restrict__ Hb,
                                              __hip_bfloat16* __restrict__ Hbt) {
    const int b  = blockIdx.z;
    const int t0 = blockIdx.x * 64;
    const int e0 = blockIdx.y * 64;
    const float* __restrict__ Hs = H + (size_t)b * DP * NP;
    __hip_bfloat16* __restrict__ Hbb  = Hb  + (size_t)b * 288 * 2048;
    __hip_bfloat16* __restrict__ Hbtb = Hbt + (size_t)b * TROWS * KLD;

    __shared__ float tile[64][65];

    const int tl = threadIdx.x & 63;
    const int er = threadIdx.x >> 6;
#pragma unroll
    for (int r = 0; r < 16; ++r) {
        const int el = er + r * 4;        // 0..63
        const int ge = e0 + el;
        const int gt = t0 + tl;
        float v = 0.f;
        if (ge < DP && gt < NP) v = Hs[(size_t)ge * NP + gt];
        tile[el][tl] = v;
        if (ge < 288 && gt < 2048) Hbb[(size_t)ge * 2048 + gt] = __float2bfloat16(v);
    }
    __syncthreads();
#pragma unroll
    for (int r = 0; r < 16; ++r) {
        const int ttl = er + r * 4;       // t-local
        const int gt = t0 + ttl;
        const int ge = e0 + tl;           // e-local = lane -> contiguous writes
        if (gt < TROWS && ge < KLD)
            Hbtb[(size_t)gt * KLD + ge] = __float2bfloat16(tile[tl][ttl]);
    }
}

// ---------------------------------------------------------------------------
// Pb[m][k] = P[m][k] (bf16, zero-padded to 288x288); Qt[n][k] = Q[k][n]
// ---------------------------------------------------------------------------
__global__ __launch_bounds__(256) void conv_pq(const float* __restrict__ P,
                                               const float* __restrict__ Q,
                                               __hip_bfloat16* __restrict__ Pb,
                                               __hip_bfloat16* __restrict__ Qt) {
    const int c0 = blockIdx.x * 64;
    const int r0 = blockIdx.y * 64;
    const int tl = threadIdx.x & 63;
    const int rr = threadIdx.x >> 6;
    __shared__ float tile[64][65];

    if (blockIdx.z == 0) {
#pragma unroll
        for (int r = 0; r < 16; ++r) {
            const int m = r0 + rr + r * 4;
            const int k = c0 + tl;
            float v = (m < DP && k < DP) ? P[m * DP + k] : 0.f;
            if (m < KLD && k < KLD) Pb[m * KLD + k] = __float2bfloat16(v);
        }
    } else {
#pragma unroll
        for (int r = 0; r < 16; ++r) {
            const int k = r0 + rr + r * 4;
            const int n = c0 + tl;
            float v = (k < DP && n < DP) ? Q[k * DP + n] : 0.f;
            tile[k - r0][n - c0] = v;
        }
        __syncthreads();
#pragma unroll
        for (int r = 0; r < 16; ++r) {
            const int k = r0 + tl;
            const int n = c0 + rr + r * 4;
            if (n < KLD && k < KLD) Qt[n * KLD + k] = __float2bfloat16(tile[tl][n - c0]);
        }
    }
}

// ---------------------------------------------------------------------------
// G[b] = Hb[b] @ Hb[b]^T  with split-K x4: one block per 32x32 output tile,
// wave s handles k in [s*512, s*512+512); 4 partial tiles summed via LDS.
// ---------------------------------------------------------------------------
__global__ __launch_bounds__(256) void gram_sk(const __hip_bfloat16* __restrict__ Hb,
                                               __hip_bfloat16* __restrict__ G) {
    const int b    = blockIdx.x / 81;
    const int tile = blockIdx.x % 81;
    const int tm = tile / 9, tn = tile % 9;
    const int s    = threadIdx.x >> 6;     // k-split id = wave id
    const int lane = threadIdx.x & 63;
    const int lrow = lane & 15;
    const int koff = (lane >> 4) * 8;
    const short* __restrict__ base = (const short*)(Hb + (size_t)b * 288 * 2048);
    const int m0 = tm * 32, n0 = tn * 32;

    __shared__ float red[4][32][32];       // 16 KB

    f32x4 acc[2][2] = {};
    const int kbeg = s * 512;
#pragma unroll 4
    for (int k0 = kbeg; k0 < kbeg + 512; k0 += 32) {
        bf16x8 a0 = *(const bf16x8*)(base + (size_t)(m0 + lrow)      * 2048 + k0 + koff);
        bf16x8 a1 = *(const bf16x8*)(base + (size_t)(m0 + 16 + lrow) * 2048 + k0 + koff);
        bf16x8 c0 = *(const bf16x8*)(base + (size_t)(n0 + lrow)      * 2048 + k0 + koff);
        bf16x8 c1 = *(const bf16x8*)(base + (size_t)(n0 + 16 + lrow) * 2048 + k0 + koff);
        acc[0][0] = __builtin_amdgcn_mfma_f32_16x16x32_bf16(a0, c0, acc[0][0], 0, 0, 0);
        acc[0][1] = __builtin_amdgcn_mfma_f32_16x16x32_bf16(a0, c1, acc[0][1], 0, 0, 0);
        acc[1][0] = __builtin_amdgcn_mfma_f32_16x16x32_bf16(a1, c0, acc[1][0], 0, 0, 0);
        acc[1][1] = __builtin_amdgcn_mfma_f32_16x16x32_bf16(a1, c1, acc[1][1], 0, 0, 0);
    }

    const int ccol  = lane & 15;
    const int crow0 = (lane >> 4) * 4;
#pragma unroll
    for (int i = 0; i < 2; ++i)
#pragma unroll
        for (int j = 0; j < 2; ++j)
#pragma unroll
            for (int r = 0; r < 4; ++r)
                red[s][i * 16 + crow0 + r][j * 16 + ccol] = acc[i][j][r];
    __syncthreads();

    // 256 threads: each sums 4 consecutive cols of one row across the 4 splits
    const int row = threadIdx.x >> 3;          // 0..31
    const int c4  = (threadIdx.x & 7) * 4;     // 0..28
    float4 v0 = *(const float4*)&red[0][row][c4];
    float4 v1 = *(const float4*)&red[1][row][c4];
    float4 v2 = *(const float4*)&red[2][row][c4];
    float4 v3 = *(const float4*)&red[3][row][c4];
    float sum[4] = {v0.x + v1.x + v2.x + v3.x,
                    v0.y + v1.y + v2.y + v3.y,
                    v0.z + v1.z + v2.z + v3.z,
                    v0.w + v1.w + v2.w + v3.w};

    const int gm = m0 + row;
    const int gn = n0 + c4;
    __hip_bfloat16 o[4];
#pragma unroll
    for (int t = 0; t < 4; ++t) {
        const float v = (gm < DP && (gn + t) < DP) ? sum[t] : 0.f;
        o[t] = __float2bfloat16(v);
    }
    __hip_bfloat16* __restrict__ Gb = G + (size_t)b * KLD * KLD;
    *(bf16x4*)&Gb[gm * KLD + gn] = *(const bf16x4*)o;
}

// ---------------------------------------------------------------------------
// C[b][m][n] = sum_k A[m][k] * B[n][k]  (both row-major along k, ld=288, K=288)
// ---------------------------------------------------------------------------
__global__ __launch_bounds__(256) void mm_mfma(const __hip_bfloat16* __restrict__ A,
                                               const __hip_bfloat16* __restrict__ B,
                                               __hip_bfloat16* __restrict__ C,
                                               int strideA, int strideB) {
    const int gw   = blockIdx.x * 4 + (threadIdx.x >> 6);
    const int b    = gw / 81;
    const int tile = gw % 81;
    const int tm = tile / 9, tn = tile % 9;
    const int lane = threadIdx.x & 63;
    const int lrow = lane & 15;
    const int koff = (lane >> 4) * 8;
    const short* __restrict__ Ab = (const short*)(A + (size_t)b * strideA);
    const short* __restrict__ Bb = (const short*)(B + (size_t)b * strideB);
    const int m0 = tm * 32, n0 = tn * 32;

    f32x4 acc[2][2] = {};
#pragma unroll
    for (int k0 = 0; k0 < KLD; k0 += 32) {
        bf16x8 a0 = *(const bf16x8*)(Ab + (m0 + lrow)      * KLD + k0 + koff);
        bf16x8 a1 = *(const bf16x8*)(Ab + (m0 + 16 + lrow) * KLD + k0 + koff);
        bf16x8 c0 = *(const bf16x8*)(Bb + (n0 + lrow)      * KLD + k0 + koff);
        bf16x8 c1 = *(const bf16x8*)(Bb + (n0 + 16 + lrow) * KLD + k0 + koff);
        acc[0][0] = __builtin_amdgcn_mfma_f32_16x16x32_bf16(a0, c0, acc[0][0], 0, 0, 0);
        acc[0][1] = __builtin_amdgcn_mfma_f32_16x16x32_bf16(a0, c1, acc[0][1], 0, 0, 0);
        acc[1][0] = __builtin_amdgcn_mfma_f32_16x16x32_bf16(a1, c0, acc[1][0], 0, 0, 0);
        acc[1][1] = __builtin_amdgcn_mfma_f32_16x16x32_bf16(a1, c1, acc[1][1], 0, 0, 0);
    }
    __hip_bfloat16* __restrict__ Cb = C + (size_t)b * KLD * KLD;
    const int ccol  = lane & 15;
    const int crow0 = (lane >> 4) * 4;
#pragma unroll
    for (int i = 0; i < 2; ++i)
#pragma unroll
        for (int j = 0; j < 2; ++j)
#pragma unroll
            for (int r = 0; r < 4; ++r) {
                const int gm = m0 + i * 16 + crow0 + r;
                const int gn = n0 + j * 16 + ccol;
                const float v = (gm < DP && gn < DP) ? acc[i][j][r] : 0.f;
                Cb[gm * KLD + gn] = __float2bfloat16(v);
            }
}

// ---------------------------------------------------------------------------
// out[b][d][t] = H[b][d][t] + (1/n) * sum_e Kb[d][e] * Hbt[t][e]
// One wave per 32(d) x 64(t) tile: 2 a-frags + 4 b-frags -> 8 MFMA / k-step.
// ---------------------------------------------------------------------------
__global__ __launch_bounds__(256) void attn_mfma(const __hip_bfloat16* __restrict__ Kb,
                                                 const __hip_bfloat16* __restrict__ Hbt,
                                                 const float* __restrict__ H,
                                                 float* __restrict__ Out) {
    const int gw   = blockIdx.x * 4 + (threadIdx.x >> 6);
    const int b    = gw / 297;            // 297 = 9 (d-tiles of 32) * 33 (t-tiles of 64)
    const int tile = gw % 297;
    const int td = tile / 33, tt = tile % 33;
    const int lane = threadIdx.x & 63;
    const int lrow = lane & 15;
    const int koff = (lane >> 4) * 8;
    const short* __restrict__ Ab = (const short*)(Kb  + (size_t)b * KLD * KLD);
    const short* __restrict__ Bb = (const short*)(Hbt + (size_t)b * TROWS * KLD);
    const int m0 = td * 32, n0 = tt * 64;

    f32x4 acc[2][4] = {};
#pragma unroll 3
    for (int k0 = 0; k0 < KLD; k0 += 32) {
        bf16x8 a0 = *(const bf16x8*)(Ab + (m0 + lrow)      * KLD + k0 + koff);
        bf16x8 a1 = *(const bf16x8*)(Ab + (m0 + 16 + lrow) * KLD + k0 + koff);
        bf16x8 bb[4];
#pragma unroll
        for (int j = 0; j < 4; ++j)
            bb[j] = *(const bf16x8*)(Bb + (size_t)(n0 + j * 16 + lrow) * KLD + k0 + koff);
#pragma unroll
        for (int j = 0; j < 4; ++j) {
            acc[0][j] = __builtin_amdgcn_mfma_f32_16x16x32_bf16(a0, bb[j], acc[0][j], 0, 0, 0);
            acc[1][j] = __builtin_amdgcn_mfma_f32_16x16x32_bf16(a1, bb[j], acc[1][j], 0, 0, 0);
        }
    }
    const float* __restrict__ Hs = H + (size_t)b * DP * NP;
    float* __restrict__ Ob = Out + (size_t)b * DP * NP;
    const float inv_n = 1.0f / (float)NSEQ;
    const int ccol  = lane & 15;
    const int crow0 = (lane >> 4) * 4;
#pragma unroll
    for (int i = 0; i < 2; ++i)
#pragma unroll
        for (int j = 0; j < 4; ++j)
#pragma unroll
            for (int r = 0; r < 4; ++r) {
                const int gd = m0 + i * 16 + crow0 + r;
                const int gt = n0 + j * 16 + ccol;
                if (gd < DP && gt < NP) {
                    const size_t idx = (size_t)gd * NP + gt;
                    Ob[idx] = Hs[idx] + inv_n * acc[i][j][r];
                }
            }
}

extern "C" void kernel_launch(void* const* d_in, const int* in_sizes, int n_in,
                              void* d_out, int out_size, void* d_ws, size_t ws_size,
                              hipStream_t stream) {
    const float* H = (const float*)d_in[0];
    const float* P = (const float*)d_in[1];
    const float* Q = (const float*)d_in[2];
    float* out = (float*)d_out;

    __hip_bfloat16* Hb  = (__hip_bfloat16*)d_ws;                   // 16*288*2048
    __hip_bfloat16* Hbt = Hb  + (size_t)NB * 288 * 2048;           // 16*2112*288
    __hip_bfloat16* G   = Hbt + (size_t)NB * TROWS * KLD;          // 16*288*288
    __hip_bfloat16* T2  = G   + (size_t)NB * KLD * KLD;
    __hip_bfloat16* Kb  = T2  + (size_t)NB * KLD * KLD;
    __hip_bfloat16* Pb  = Kb  + (size_t)NB * KLD * KLD;
    __hip_bfloat16* Qt  = Pb  + (size_t)KLD * KLD;

    conv_h <<<dim3(33, 5, NB), 256, 0, stream>>>(H, Hb, Hbt);
    conv_pq<<<dim3(5, 5, 2),   256, 0, stream>>>(P, Q, Pb, Qt);
    // G[b] = H-hat @ H-hat^T  (split-K x4, in-block reduce)
    gram_sk<<<dim3(NB * 81), 256, 0, stream>>>(Hb, G);
    // T2[b] = Q^T @ G[b]   (B-frags read G rows, valid by symmetry of G)
    mm_mfma<<<dim3(324), 256, 0, stream>>>(Qt, G, T2, 0, KLD * KLD);
    // K[b] = P @ T2[b]^T = P @ G @ Q
    mm_mfma<<<dim3(324), 256, 0, stream>>>(Pb, T2, Kb, 0, KLD * KLD);
    // out = H + (K @ H) / n
    attn_mfma<<<dim3(1188), 256, 0, stream>>>(Kb, Hbt, H, out);
}